// Round 7
// baseline (277.214 us; speedup 1.0000x reference)
//
#include <hip/hip_runtime.h>

#define N_NODESC 50000
#define E0C      800000
#define E_TOTC   850000
#define IN_CHC   128
#define HCC      128   // HEADS*HID
#define HEADSC   4
#define OUT_CHC  16
#define NEG_SLOPE 0.2f
#define NBLK     ((N_NODESC + 255) / 256)   // 196
#define G1_ROWS  32                          // rows per block in k_gemm1
#define GRP      8                           // dst-space partitions (≈ XCDs)
#define BPG      32                          // blocks per group
#define DPART    (N_NODESC/GRP)              // 6250 dst per group

__device__ __forceinline__ float lrelu(float v){ return v > 0.f ? v : NEG_SLOPE * v; }

// round-to-nearest-even fp32 -> bf16 (as uint16 in low bits)
__device__ __forceinline__ unsigned int f2bf(float f){
  unsigned int b = __float_as_uint(f);
  return (b + 0x7fffu + ((b >> 16) & 1u)) >> 16;
}
__device__ __forceinline__ float bf2f(unsigned int lo16){
  return __uint_as_float(lo16 << 16);
}

// h1 = x @ W1 (stored bf16-packed: uint = [c0+1 | c0]); al_s/al_d from fp32 accs.
__global__ void __launch_bounds__(256) k_gemm1(const float* __restrict__ x, const float* __restrict__ W1,
        const float* __restrict__ a_s, const float* __restrict__ a_d,
        unsigned int* __restrict__ h1b, float* __restrict__ al_s, float* __restrict__ al_d)
{
  __shared__ __align__(16) float Wl[IN_CHC*HCC];        // 64 KB
  __shared__ __align__(16) float xT[IN_CHC][G1_ROWS];   // 16 KB, [k][row]
  int tid = threadIdx.x;
  for (int i = tid*4; i < IN_CHC*HCC; i += 256*4)
    *(float4*)&Wl[i] = *(const float4*)&W1[i];
  int row0 = blockIdx.x * G1_ROWS;
  {
    int r  = tid >> 3;          // 0..31
    int kc = (tid & 7) * 16;    // 0..112
    int rr = row0 + r; if (rr > N_NODESC-1) rr = N_NODESC-1;   // clamp OOB reads
    const float* xp = &x[(size_t)rr*IN_CHC + kc];
    #pragma unroll
    for (int j = 0; j < 16; j += 4){
      float4 v = *(const float4*)&xp[j];
      xT[kc+j+0][r] = v.x;
      xT[kc+j+1][r] = v.y;
      xT[kc+j+2][r] = v.z;
      xT[kc+j+3][r] = v.w;
    }
  }
  __syncthreads();
  int wave = tid >> 6, lane = tid & 63;
  int c0 = lane * 2;
  int rbase = wave * 8;
  float acc[8][2];
  #pragma unroll
  for (int j = 0; j < 8; j++){ acc[j][0] = 0.f; acc[j][1] = 0.f; }
  #pragma unroll 4
  for (int k = 0; k < IN_CHC; k++){
    float2 w  = *(const float2*)&Wl[k*HCC + c0];
    float4 xa = *(const float4*)&xT[k][rbase];      // rows rbase..+3 (uniform)
    float4 xb = *(const float4*)&xT[k][rbase+4];    // rows rbase+4..+7 (uniform)
    acc[0][0] = fmaf(xa.x, w.x, acc[0][0]); acc[0][1] = fmaf(xa.x, w.y, acc[0][1]);
    acc[1][0] = fmaf(xa.y, w.x, acc[1][0]); acc[1][1] = fmaf(xa.y, w.y, acc[1][1]);
    acc[2][0] = fmaf(xa.z, w.x, acc[2][0]); acc[2][1] = fmaf(xa.z, w.y, acc[2][1]);
    acc[3][0] = fmaf(xa.w, w.x, acc[3][0]); acc[3][1] = fmaf(xa.w, w.y, acc[3][1]);
    acc[4][0] = fmaf(xb.x, w.x, acc[4][0]); acc[4][1] = fmaf(xb.x, w.y, acc[4][1]);
    acc[5][0] = fmaf(xb.y, w.x, acc[5][0]); acc[5][1] = fmaf(xb.y, w.y, acc[5][1]);
    acc[6][0] = fmaf(xb.z, w.x, acc[6][0]); acc[6][1] = fmaf(xb.z, w.y, acc[6][1]);
    acc[7][0] = fmaf(xb.w, w.x, acc[7][0]); acc[7][1] = fmaf(xb.w, w.y, acc[7][1]);
  }
  float as0 = a_s[c0], as1 = a_s[c0+1];
  float ad0 = a_d[c0], ad1 = a_d[c0+1];
  #pragma unroll
  for (int j = 0; j < 8; j++){
    int row = row0 + rbase + j;
    if (row >= N_NODESC) break;
    h1b[(size_t)row*64 + lane] = f2bf(acc[j][0]) | (f2bf(acc[j][1]) << 16);
    float ps = acc[j][0]*as0 + acc[j][1]*as1;
    float pd = acc[j][0]*ad0 + acc[j][1]*ad1;
    #pragma unroll
    for (int m = 1; m < 16; m <<= 1){ ps += __shfl_xor(ps, m, 64); pd += __shfl_xor(pd, m, 64); }
    if ((lane & 15) == 0){
      al_s[row*HEADSC + (lane>>4)] = ps;
      al_d[row*HEADSC + (lane>>4)] = pd;
    }
  }
}

// dst-partitioned histogram: group g = blockIdx&7 owns dst [g*6250, (g+1)*6250).
// Each group scans all edges (coalesced, L3-served); atomics stay XCD-local.
__global__ void __launch_bounds__(256) k_hist(const int* __restrict__ ei, int* __restrict__ deg){
  int g  = blockIdx.x & (GRP-1);
  int bg = blockIdx.x >> 3;
  int lo = g * DPART;
  int t  = bg*256 + threadIdx.x;
  const int stride = BPG*256;
  for (int e = t; e < E_TOTC; e += stride){
    int d = (e < E0C) ? ei[E0C + e] : (e - E0C);
    if ((unsigned)(d - lo) < (unsigned)DPART) atomicAdd(&deg[d], 1);
  }
}

// --- multi-block exclusive scan of deg -> rp, nxt ---
__global__ void __launch_bounds__(256) k_blocksum(const int* __restrict__ deg, int* __restrict__ bsum){
  int i = blockIdx.x*256 + threadIdx.x;
  int v = (i < N_NODESC) ? deg[i] : 0;
  #pragma unroll
  for (int o = 1; o < 64; o <<= 1) v += __shfl_xor(v, o, 64);
  __shared__ int ws[4];
  if ((threadIdx.x & 63) == 0) ws[threadIdx.x >> 6] = v;
  __syncthreads();
  if (threadIdx.x == 0) bsum[blockIdx.x] = ws[0] + ws[1] + ws[2] + ws[3];
}

__global__ void __launch_bounds__(256) k_scanbsum(const int* __restrict__ bsum, int* __restrict__ boff, int* __restrict__ rp_last){
  __shared__ int buf[256];
  int tid = threadIdx.x;
  int v = (tid < NBLK) ? bsum[tid] : 0;
  buf[tid] = v; __syncthreads();
  #pragma unroll
  for (int off = 1; off < 256; off <<= 1){
    int t = (tid >= off) ? buf[tid - off] : 0;
    __syncthreads();
    buf[tid] += t; __syncthreads();
  }
  if (tid < NBLK) boff[tid] = buf[tid] - v;  // exclusive
  if (tid == 255) rp_last[0] = buf[255];     // total = rp[N]
}

__global__ void __launch_bounds__(256) k_scanblock(const int* __restrict__ deg, const int* __restrict__ boff,
                                                   int* __restrict__ rp, int* __restrict__ nxt){
  __shared__ int buf[256];
  int tid = threadIdx.x;
  int i = blockIdx.x*256 + tid;
  int v = (i < N_NODESC) ? deg[i] : 0;
  buf[tid] = v; __syncthreads();
  #pragma unroll
  for (int off = 1; off < 256; off <<= 1){
    int t = (tid >= off) ? buf[tid - off] : 0;
    __syncthreads();
    buf[tid] += t; __syncthreads();
  }
  if (i < N_NODESC){
    int ex = boff[blockIdx.x] + buf[tid] - v;
    rp[i] = ex; nxt[i] = ex;
  }
}

// dst-partitioned scatter: group writes only its contiguous srcs chunk
// (rp monotonic in dst) -> lines stay in one L2 and combine.
__global__ void __launch_bounds__(256) k_scatter(const int* __restrict__ ei, int* __restrict__ nxt, int* __restrict__ srcs){
  int g  = blockIdx.x & (GRP-1);
  int bg = blockIdx.x >> 3;
  int lo = g * DPART;
  int t  = bg*256 + threadIdx.x;
  const int stride = BPG*256;
  for (int e = t; e < E_TOTC; e += stride){
    int s, d;
    if (e < E0C){ d = ei[E0C + e]; s = ei[e]; }
    else { s = e - E0C; d = s; }
    if ((unsigned)(d - lo) < (unsigned)DPART){
      int pos = atomicAdd(&nxt[d], 1);
      srcs[pos] = s;
    }
  }
}

// Layer-1. exp store + denom (pass A), bf16 gather + FMA aggregate (pass B).
__global__ void __launch_bounds__(256) k_node1(const unsigned int* __restrict__ h1b,
        const float* __restrict__ al_s, const float* __restrict__ al_d,
        const int* __restrict__ rp, const int* __restrict__ srcs,
        const float* __restrict__ b1, float* __restrict__ hout, float* __restrict__ exb)
{
  int wave = threadIdx.x >> 6, lane = threadIdx.x & 63;
  int n = blockIdx.x*4 + wave;
  if (n >= N_NODESC) return;
  int beg = rp[n], end = rp[n+1];
  float4 ad4 = *(const float4*)&al_d[n*4];
  float d0=0.f, d1=0.f, d2=0.f, d3=0.f;
  for (int p = beg + lane; p < end; p += 64){
    int s = srcs[p];
    float4 as = *(const float4*)&al_s[s*4];
    float4 ex;
    ex.x = expf(lrelu(as.x + ad4.x));
    ex.y = expf(lrelu(as.y + ad4.y));
    ex.z = expf(lrelu(as.z + ad4.z));
    ex.w = expf(lrelu(as.w + ad4.w));
    *(float4*)&exb[(size_t)p*4] = ex;
    d0 += ex.x; d1 += ex.y; d2 += ex.z; d3 += ex.w;
  }
  #pragma unroll
  for (int o = 1; o < 64; o <<= 1){
    d0 += __shfl_xor(d0, o, 64);
    d1 += __shfl_xor(d1, o, 64);
    d2 += __shfl_xor(d2, o, 64);
    d3 += __shfl_xor(d3, o, 64);
  }
  __threadfence_block();
  int h = lane >> 4;
  float dh  = (h==0) ? d0 : (h==1) ? d1 : (h==2) ? d2 : d3;
  float inv = 1.f / (dh + 1e-16f);
  float acc0 = 0.f, acc1 = 0.f;
  #pragma unroll 4
  for (int p = beg; p < end; p++){
    float a = exb[(size_t)p*4 + h];
    unsigned int u = h1b[(size_t)srcs[p]*64 + lane];
    acc0 = fmaf(a, bf2f(u & 0xffffu), acc0);
    acc1 = fmaf(a, bf2f(u >> 16), acc1);
  }
  int c0 = lane*2;
  float o0 = acc0*inv + b1[c0], o1 = acc1*inv + b1[c0+1];
  o0 = o0 > 0.f ? o0 : expf(o0) - 1.f;   // ELU
  o1 = o1 > 0.f ? o1 : expf(o1) - 1.f;
  *(float2*)&hout[(size_t)n*HCC + c0] = make_float2(o0, o1);
}

// h2 = hout @ W2 ; scalar attention logits (H=1,C=16). 4 rows per wave.
__global__ void __launch_bounds__(256) k_gemm2(const float* __restrict__ hin, const float* __restrict__ W2,
        const float* __restrict__ a_s, const float* __restrict__ a_d,
        float* __restrict__ h2, float* __restrict__ al_s, float* __restrict__ al_d)
{
  __shared__ __align__(16) float Wl[IN_CHC*OUT_CHC];   // 8 KB
  __shared__ __align__(16) float xr[4][4][IN_CHC];     // 8 KB
  int tid = threadIdx.x;
  for (int i = tid*4; i < IN_CHC*OUT_CHC; i += 256*4)
    *(float4*)&Wl[i] = *(const float4*)&W2[i];
  __syncthreads();
  int wave = tid >> 6, lane = tid & 63;
  int r = lane >> 4, c = lane & 15;
  int row0 = blockIdx.x*16 + wave*4;
  for (int rr = 0; rr < 4; rr++){
    float2 v = *(const float2*)&hin[(size_t)(row0+rr)*IN_CHC + lane*2];
    *(float2*)&xr[wave][rr][lane*2] = v;
  }
  float acc = 0.f;
  #pragma unroll 8
  for (int k = 0; k < IN_CHC; k++)
    acc = fmaf(xr[wave][r][k], Wl[k*OUT_CHC + c], acc);
  int row = row0 + r;
  h2[row*OUT_CHC + c] = acc;
  float ps = acc * a_s[c];
  float pd = acc * a_d[c];
  #pragma unroll
  for (int m = 1; m < 16; m <<= 1){ ps += __shfl_xor(ps, m, 64); pd += __shfl_xor(pd, m, 64); }
  if (c == 0){ al_s[row] = ps; al_d[row] = pd; }
}

// Layer-2: exp store + denom + aggregate + log_softmax (no max subtraction).
__global__ void __launch_bounds__(256) k_node2(const float* __restrict__ h2,
        const float* __restrict__ al_s, const float* __restrict__ al_d,
        const int* __restrict__ rp, const int* __restrict__ srcs,
        const float* __restrict__ b2, float* __restrict__ out, float* __restrict__ exb)
{
  int wave = threadIdx.x >> 6, lane = threadIdx.x & 63;
  int n = blockIdx.x*4 + wave;
  if (n >= N_NODESC) return;
  int beg = rp[n], end = rp[n+1];
  float ad = al_d[n];
  float den = 0.f;
  for (int p = beg + lane; p < end; p += 64){
    float ex = expf(lrelu(al_s[srcs[p]] + ad));
    exb[p] = ex;
    den += ex;
  }
  #pragma unroll
  for (int o = 1; o < 64; o <<= 1) den += __shfl_xor(den, o, 64);
  __threadfence_block();
  float inv = 1.f / (den + 1e-16f);
  int c = lane & 15, j = lane >> 4;
  float acc = 0.f;
  #pragma unroll 4
  for (int p = beg + j; p < end; p += 4){
    int s = srcs[p];
    acc = fmaf(exb[p], h2[s*OUT_CHC + c], acc);
  }
  acc += __shfl_xor(acc, 16, 64);
  acc += __shfl_xor(acc, 32, 64);
  float v = acc*inv + b2[c];
  float mm = v;
  #pragma unroll
  for (int o = 1; o < 16; o <<= 1) mm = fmaxf(mm, __shfl_xor(mm, o, 64));
  float se = expf(v - mm);
  #pragma unroll
  for (int o = 1; o < 16; o <<= 1) se += __shfl_xor(se, o, 64);
  if (j == 0) out[n*OUT_CHC + c] = v - mm - logf(se);
}

extern "C" void kernel_launch(void* const* d_in, const int* in_sizes, int n_in,
                              void* d_out, int out_size, void* d_ws, size_t ws_size,
                              hipStream_t stream)
{
  const float* x   = (const float*)d_in[0];
  const int*   ei  = (const int*)d_in[1];
  // d_in[2] edge_attr: ignored (PyG GATConv with edge_dim=None)
  const float* W1  = (const float*)d_in[3];
  const float* as1 = (const float*)d_in[4];
  const float* ad1 = (const float*)d_in[5];
  const float* b1  = (const float*)d_in[6];
  const float* W2  = (const float*)d_in[7];
  const float* as2 = (const float*)d_in[8];
  const float* ad2 = (const float*)d_in[9];
  const float* b2  = (const float*)d_in[10];
  float* out = (float*)d_out;

  char* ws = (char*)d_ws;
  size_t off = 0;
  auto alloc = [&](size_t bytes)->void*{
    void* p = ws + off;
    off = (off + bytes + 255) & ~(size_t)255;
    return p;
  };
  unsigned int* h1b = (unsigned int*)alloc((size_t)N_NODESC*64*4);  // bf16-packed, 12.8 MB
  float* hout  = (float*)alloc((size_t)N_NODESC*HCC*4);
  float* al_s1 = (float*)alloc((size_t)N_NODESC*HEADSC*4);
  float* al_d1 = (float*)alloc((size_t)N_NODESC*HEADSC*4);
  float* h2    = (float*)alloc((size_t)N_NODESC*OUT_CHC*4);
  float* al_s2 = (float*)alloc((size_t)N_NODESC*4);
  float* al_d2 = (float*)alloc((size_t)N_NODESC*4);
  int* deg     = (int*)alloc((size_t)N_NODESC*4);
  int* rp      = (int*)alloc((size_t)(N_NODESC+1)*4);
  int* nxt     = (int*)alloc((size_t)N_NODESC*4);
  int* srcs    = (int*)alloc((size_t)E_TOTC*4);
  int* bsum    = (int*)alloc((size_t)NBLK*4);
  int* boff    = (int*)alloc((size_t)NBLK*4);
  float* exb1  = (float*)alloc((size_t)E_TOTC*HEADSC*4);  // 13.6 MB
  float* exb2  = (float*)alloc((size_t)E_TOTC*4);         // 3.4 MB

  hipMemsetAsync(deg, 0, (size_t)N_NODESC*4, stream);
  k_gemm1<<<(N_NODESC+G1_ROWS-1)/G1_ROWS, 256, 0, stream>>>(x, W1, as1, ad1, h1b, al_s1, al_d1);
  k_hist<<<GRP*BPG, 256, 0, stream>>>(ei, deg);
  k_blocksum<<<NBLK, 256, 0, stream>>>(deg, bsum);
  k_scanbsum<<<1, 256, 0, stream>>>(bsum, boff, rp + N_NODESC);
  k_scanblock<<<NBLK, 256, 0, stream>>>(deg, boff, rp, nxt);
  k_scatter<<<GRP*BPG, 256, 0, stream>>>(ei, nxt, srcs);
  k_node1<<<(N_NODESC+3)/4, 256, 0, stream>>>(h1b, al_s1, al_d1, rp, srcs, b1, hout, exb1);
  k_gemm2<<<N_NODESC/16, 256, 0, stream>>>(hout, W2, as2, ad2, h2, al_s2, al_d2);
  k_node2<<<(N_NODESC+3)/4, 256, 0, stream>>>(h2, al_s2, al_d2, rp, srcs, b2, out, exb2);
}

// Round 8
// 185.837 us; speedup vs baseline: 1.4917x; 1.4917x over previous
//
#include <hip/hip_runtime.h>

#define N_NODESC 50000
#define E0C      800000
#define E_TOTC   850000
#define IN_CHC   128
#define HCC      128   // HEADS*HID
#define HEADSC   4
#define OUT_CHC  16
#define NEG_SLOPE 0.2f
#define G1_ROWS  32                          // rows per block in k_gemm1
#define NBUCK    196                         // ceil(50000/256) dst buckets
#define BNODES   256                         // nodes per bucket (dst>>8)
#define SBLK     128                         // binning blocks
#define CHUNK    6656                        // edges per binning block (128*6656 >= 850000)

__device__ __forceinline__ float lrelu(float v){ return v > 0.f ? v : NEG_SLOPE * v; }

// round-to-nearest-even fp32 -> bf16 (as uint16 in low bits)
__device__ __forceinline__ unsigned int f2bf(float f){
  unsigned int b = __float_as_uint(f);
  return (b + 0x7fffu + ((b >> 16) & 1u)) >> 16;
}
__device__ __forceinline__ float bf2f(unsigned int lo16){
  return __uint_as_float(lo16 << 16);
}

// h1 = x @ W1 (stored bf16-packed: uint = [c0+1 | c0]); al_s/al_d from fp32 accs.
__global__ void __launch_bounds__(256) k_gemm1(const float* __restrict__ x, const float* __restrict__ W1,
        const float* __restrict__ a_s, const float* __restrict__ a_d,
        unsigned int* __restrict__ h1b, float* __restrict__ al_s, float* __restrict__ al_d)
{
  __shared__ __align__(16) float Wl[IN_CHC*HCC];        // 64 KB
  __shared__ __align__(16) float xT[IN_CHC][G1_ROWS];   // 16 KB, [k][row]
  int tid = threadIdx.x;
  for (int i = tid*4; i < IN_CHC*HCC; i += 256*4)
    *(float4*)&Wl[i] = *(const float4*)&W1[i];
  int row0 = blockIdx.x * G1_ROWS;
  {
    int r  = tid >> 3;          // 0..31
    int kc = (tid & 7) * 16;    // 0..112
    int rr = row0 + r; if (rr > N_NODESC-1) rr = N_NODESC-1;   // clamp OOB reads
    const float* xp = &x[(size_t)rr*IN_CHC + kc];
    #pragma unroll
    for (int j = 0; j < 16; j += 4){
      float4 v = *(const float4*)&xp[j];
      xT[kc+j+0][r] = v.x;
      xT[kc+j+1][r] = v.y;
      xT[kc+j+2][r] = v.z;
      xT[kc+j+3][r] = v.w;
    }
  }
  __syncthreads();
  int wave = tid >> 6, lane = tid & 63;
  int c0 = lane * 2;
  int rbase = wave * 8;
  float acc[8][2];
  #pragma unroll
  for (int j = 0; j < 8; j++){ acc[j][0] = 0.f; acc[j][1] = 0.f; }
  #pragma unroll 4
  for (int k = 0; k < IN_CHC; k++){
    float2 w  = *(const float2*)&Wl[k*HCC + c0];
    float4 xa = *(const float4*)&xT[k][rbase];      // rows rbase..+3 (uniform)
    float4 xb = *(const float4*)&xT[k][rbase+4];    // rows rbase+4..+7 (uniform)
    acc[0][0] = fmaf(xa.x, w.x, acc[0][0]); acc[0][1] = fmaf(xa.x, w.y, acc[0][1]);
    acc[1][0] = fmaf(xa.y, w.x, acc[1][0]); acc[1][1] = fmaf(xa.y, w.y, acc[1][1]);
    acc[2][0] = fmaf(xa.z, w.x, acc[2][0]); acc[2][1] = fmaf(xa.z, w.y, acc[2][1]);
    acc[3][0] = fmaf(xa.w, w.x, acc[3][0]); acc[3][1] = fmaf(xa.w, w.y, acc[3][1]);
    acc[4][0] = fmaf(xb.x, w.x, acc[4][0]); acc[4][1] = fmaf(xb.x, w.y, acc[4][1]);
    acc[5][0] = fmaf(xb.y, w.x, acc[5][0]); acc[5][1] = fmaf(xb.y, w.y, acc[5][1]);
    acc[6][0] = fmaf(xb.z, w.x, acc[6][0]); acc[6][1] = fmaf(xb.z, w.y, acc[6][1]);
    acc[7][0] = fmaf(xb.w, w.x, acc[7][0]); acc[7][1] = fmaf(xb.w, w.y, acc[7][1]);
  }
  float as0 = a_s[c0], as1 = a_s[c0+1];
  float ad0 = a_d[c0], ad1 = a_d[c0+1];
  #pragma unroll
  for (int j = 0; j < 8; j++){
    int row = row0 + rbase + j;
    if (row >= N_NODESC) break;
    h1b[(size_t)row*64 + lane] = f2bf(acc[j][0]) | (f2bf(acc[j][1]) << 16);
    float ps = acc[j][0]*as0 + acc[j][1]*as1;
    float pd = acc[j][0]*ad0 + acc[j][1]*ad1;
    #pragma unroll
    for (int m = 1; m < 16; m <<= 1){ ps += __shfl_xor(ps, m, 64); pd += __shfl_xor(pd, m, 64); }
    if ((lane & 15) == 0){
      al_s[row*HEADSC + (lane>>4)] = ps;
      al_d[row*HEADSC + (lane>>4)] = pd;
    }
  }
}

// --- binned CSR build: A) per-block bucket hist, scan) offsets, B) bin write, C) per-bucket scatter ---
__global__ void __launch_bounds__(256) k_binA(const int* __restrict__ ei, int* __restrict__ bh){
  __shared__ int h[NBUCK];
  int tid = threadIdx.x, b = blockIdx.x;
  for (int i = tid; i < NBUCK; i += 256) h[i] = 0;
  __syncthreads();
  int e0 = b*CHUNK, e1 = e0 + CHUNK; if (e1 > E_TOTC) e1 = E_TOTC;
  for (int e = e0 + tid; e < e1; e += 256){
    int d = (e < E0C) ? ei[E0C + e] : (e - E0C);
    atomicAdd(&h[d >> 8], 1);
  }
  __syncthreads();
  for (int i = tid; i < NBUCK; i += 256) bh[b*NBUCK + i] = h[i];
}

// single block: bh[b][k] -> per-(block,bucket) base in binbuf; bstart[k] = CSR/bin start per bucket
__global__ void __launch_bounds__(256) k_binscan(int* __restrict__ bh, int* __restrict__ bstart){
  __shared__ int buf[256];
  int tid = threadIdx.x;
  int tot = 0;
  if (tid < NBUCK)
    for (int b = 0; b < SBLK; b++) tot += bh[b*NBUCK + tid];
  buf[tid] = (tid < NBUCK) ? tot : 0;
  __syncthreads();
  #pragma unroll
  for (int off = 1; off < 256; off <<= 1){
    int t = (tid >= off) ? buf[tid - off] : 0;
    __syncthreads();
    buf[tid] += t; __syncthreads();
  }
  int excl = buf[tid] - ((tid < NBUCK) ? tot : 0);
  if (tid < NBUCK) bstart[tid] = excl;
  if (tid == 0) bstart[NBUCK] = E_TOTC;
  __syncthreads();
  if (tid < NBUCK){
    int run = excl;
    for (int b = 0; b < SBLK; b++){
      int t = bh[b*NBUCK + tid];
      bh[b*NBUCK + tid] = run;
      run += t;
    }
  }
}

__global__ void __launch_bounds__(256) k_binB(const int* __restrict__ ei, const int* __restrict__ bh,
                                              unsigned int* __restrict__ binbuf){
  __shared__ int h[NBUCK];
  int tid = threadIdx.x, b = blockIdx.x;
  for (int i = tid; i < NBUCK; i += 256) h[i] = bh[b*NBUCK + i];
  __syncthreads();
  int e0 = b*CHUNK, e1 = e0 + CHUNK; if (e1 > E_TOTC) e1 = E_TOTC;
  for (int e = e0 + tid; e < e1; e += 256){
    int s, d;
    if (e < E0C){ d = ei[E0C + e]; s = ei[e]; }
    else { s = e - E0C; d = s; }
    int pos = atomicAdd(&h[d >> 8], 1);
    binbuf[pos] = ((unsigned int)d << 16) | (unsigned int)s;
  }
}

// one block per bucket: local hist -> scan -> rp + final srcs scatter (L2-local writes)
__global__ void __launch_bounds__(256) k_binC(const unsigned int* __restrict__ binbuf,
                                              const int* __restrict__ bstart,
                                              int* __restrict__ rp, int* __restrict__ srcs){
  __shared__ int lcnt[BNODES];
  __shared__ int buf[BNODES];
  __shared__ int pfx[BNODES];
  int tid = threadIdx.x, k = blockIdx.x;
  int lo = k * BNODES;
  int b0 = bstart[k], b1 = bstart[k+1];
  lcnt[tid] = 0;
  __syncthreads();
  for (int i = b0 + tid; i < b1; i += 256){
    int d = binbuf[i] >> 16;
    atomicAdd(&lcnt[d - lo], 1);
  }
  __syncthreads();
  int v = lcnt[tid];
  buf[tid] = v;
  __syncthreads();
  #pragma unroll
  for (int off = 1; off < 256; off <<= 1){
    int t = (tid >= off) ? buf[tid - off] : 0;
    __syncthreads();
    buf[tid] += t; __syncthreads();
  }
  int excl = buf[tid] - v;
  pfx[tid] = excl;
  int node = lo + tid;
  if (node < N_NODESC) rp[node] = b0 + excl;
  if (k == 0 && tid == 0) rp[N_NODESC] = E_TOTC;
  lcnt[tid] = 0;
  __syncthreads();
  for (int i = b0 + tid; i < b1; i += 256){
    unsigned int u = binbuf[i];
    int d = u >> 16;
    int r = atomicAdd(&lcnt[d - lo], 1);
    srcs[b0 + pfx[d - lo] + r] = (int)(u & 0xffffu);
  }
}

// Layer-1. exp store + denom (pass A), bf16 gather + FMA aggregate (pass B).
__global__ void __launch_bounds__(256) k_node1(const unsigned int* __restrict__ h1b,
        const float* __restrict__ al_s, const float* __restrict__ al_d,
        const int* __restrict__ rp, const int* __restrict__ srcs,
        const float* __restrict__ b1, float* __restrict__ hout, float* __restrict__ exb)
{
  int wave = threadIdx.x >> 6, lane = threadIdx.x & 63;
  int n = blockIdx.x*4 + wave;
  if (n >= N_NODESC) return;
  int beg = rp[n], end = rp[n+1];
  float4 ad4 = *(const float4*)&al_d[n*4];
  float d0=0.f, d1=0.f, d2=0.f, d3=0.f;
  for (int p = beg + lane; p < end; p += 64){
    int s = srcs[p];
    float4 as = *(const float4*)&al_s[s*4];
    float4 ex;
    ex.x = expf(lrelu(as.x + ad4.x));
    ex.y = expf(lrelu(as.y + ad4.y));
    ex.z = expf(lrelu(as.z + ad4.z));
    ex.w = expf(lrelu(as.w + ad4.w));
    *(float4*)&exb[(size_t)p*4] = ex;
    d0 += ex.x; d1 += ex.y; d2 += ex.z; d3 += ex.w;
  }
  #pragma unroll
  for (int o = 1; o < 64; o <<= 1){
    d0 += __shfl_xor(d0, o, 64);
    d1 += __shfl_xor(d1, o, 64);
    d2 += __shfl_xor(d2, o, 64);
    d3 += __shfl_xor(d3, o, 64);
  }
  __threadfence_block();
  int h = lane >> 4;
  float dh  = (h==0) ? d0 : (h==1) ? d1 : (h==2) ? d2 : d3;
  float inv = 1.f / (dh + 1e-16f);
  float acc0 = 0.f, acc1 = 0.f;
  #pragma unroll 4
  for (int p = beg; p < end; p++){
    float a = exb[(size_t)p*4 + h];
    unsigned int u = h1b[(size_t)srcs[p]*64 + lane];
    acc0 = fmaf(a, bf2f(u & 0xffffu), acc0);
    acc1 = fmaf(a, bf2f(u >> 16), acc1);
  }
  int c0 = lane*2;
  float o0 = acc0*inv + b1[c0], o1 = acc1*inv + b1[c0+1];
  o0 = o0 > 0.f ? o0 : expf(o0) - 1.f;   // ELU
  o1 = o1 > 0.f ? o1 : expf(o1) - 1.f;
  *(float2*)&hout[(size_t)n*HCC + c0] = make_float2(o0, o1);
}

// h2 = hout @ W2 ; scalar attention logits (H=1,C=16). 4 rows per wave.
__global__ void __launch_bounds__(256) k_gemm2(const float* __restrict__ hin, const float* __restrict__ W2,
        const float* __restrict__ a_s, const float* __restrict__ a_d,
        float* __restrict__ h2, float* __restrict__ al_s, float* __restrict__ al_d)
{
  __shared__ __align__(16) float Wl[IN_CHC*OUT_CHC];   // 8 KB
  __shared__ __align__(16) float xr[4][4][IN_CHC];     // 8 KB
  int tid = threadIdx.x;
  for (int i = tid*4; i < IN_CHC*OUT_CHC; i += 256*4)
    *(float4*)&Wl[i] = *(const float4*)&W2[i];
  __syncthreads();
  int wave = tid >> 6, lane = tid & 63;
  int r = lane >> 4, c = lane & 15;
  int row0 = blockIdx.x*16 + wave*4;
  for (int rr = 0; rr < 4; rr++){
    float2 v = *(const float2*)&hin[(size_t)(row0+rr)*IN_CHC + lane*2];
    *(float2*)&xr[wave][rr][lane*2] = v;
  }
  float acc = 0.f;
  #pragma unroll 8
  for (int k = 0; k < IN_CHC; k++)
    acc = fmaf(xr[wave][r][k], Wl[k*OUT_CHC + c], acc);
  int row = row0 + r;
  h2[row*OUT_CHC + c] = acc;
  float ps = acc * a_s[c];
  float pd = acc * a_d[c];
  #pragma unroll
  for (int m = 1; m < 16; m <<= 1){ ps += __shfl_xor(ps, m, 64); pd += __shfl_xor(pd, m, 64); }
  if (c == 0){ al_s[row] = ps; al_d[row] = pd; }
}

// Layer-2: exp store + denom + aggregate + log_softmax (no max subtraction).
__global__ void __launch_bounds__(256) k_node2(const float* __restrict__ h2,
        const float* __restrict__ al_s, const float* __restrict__ al_d,
        const int* __restrict__ rp, const int* __restrict__ srcs,
        const float* __restrict__ b2, float* __restrict__ out, float* __restrict__ exb)
{
  int wave = threadIdx.x >> 6, lane = threadIdx.x & 63;
  int n = blockIdx.x*4 + wave;
  if (n >= N_NODESC) return;
  int beg = rp[n], end = rp[n+1];
  float ad = al_d[n];
  float den = 0.f;
  for (int p = beg + lane; p < end; p += 64){
    float ex = expf(lrelu(al_s[srcs[p]] + ad));
    exb[p] = ex;
    den += ex;
  }
  #pragma unroll
  for (int o = 1; o < 64; o <<= 1) den += __shfl_xor(den, o, 64);
  __threadfence_block();
  float inv = 1.f / (den + 1e-16f);
  int c = lane & 15, j = lane >> 4;
  float acc = 0.f;
  #pragma unroll 4
  for (int p = beg + j; p < end; p += 4){
    int s = srcs[p];
    acc = fmaf(exb[p], h2[s*OUT_CHC + c], acc);
  }
  acc += __shfl_xor(acc, 16, 64);
  acc += __shfl_xor(acc, 32, 64);
  float v = acc*inv + b2[c];
  float mm = v;
  #pragma unroll
  for (int o = 1; o < 16; o <<= 1) mm = fmaxf(mm, __shfl_xor(mm, o, 64));
  float se = expf(v - mm);
  #pragma unroll
  for (int o = 1; o < 16; o <<= 1) se += __shfl_xor(se, o, 64);
  if (j == 0) out[n*OUT_CHC + c] = v - mm - logf(se);
}

extern "C" void kernel_launch(void* const* d_in, const int* in_sizes, int n_in,
                              void* d_out, int out_size, void* d_ws, size_t ws_size,
                              hipStream_t stream)
{
  const float* x   = (const float*)d_in[0];
  const int*   ei  = (const int*)d_in[1];
  // d_in[2] edge_attr: ignored (PyG GATConv with edge_dim=None)
  const float* W1  = (const float*)d_in[3];
  const float* as1 = (const float*)d_in[4];
  const float* ad1 = (const float*)d_in[5];
  const float* b1  = (const float*)d_in[6];
  const float* W2  = (const float*)d_in[7];
  const float* as2 = (const float*)d_in[8];
  const float* ad2 = (const float*)d_in[9];
  const float* b2  = (const float*)d_in[10];
  float* out = (float*)d_out;

  char* ws = (char*)d_ws;
  size_t off = 0;
  auto alloc = [&](size_t bytes)->void*{
    void* p = ws + off;
    off = (off + bytes + 255) & ~(size_t)255;
    return p;
  };
  unsigned int* h1b = (unsigned int*)alloc((size_t)N_NODESC*64*4);  // bf16-packed, 12.8 MB
  float* hout  = (float*)alloc((size_t)N_NODESC*HCC*4);
  float* al_s1 = (float*)alloc((size_t)N_NODESC*HEADSC*4);
  float* al_d1 = (float*)alloc((size_t)N_NODESC*HEADSC*4);
  float* h2    = (float*)alloc((size_t)N_NODESC*OUT_CHC*4);
  float* al_s2 = (float*)alloc((size_t)N_NODESC*4);
  float* al_d2 = (float*)alloc((size_t)N_NODESC*4);
  int* rp      = (int*)alloc((size_t)(N_NODESC+1)*4);
  int* srcs    = (int*)alloc((size_t)E_TOTC*4);
  int* bh      = (int*)alloc((size_t)SBLK*NBUCK*4);        // 100 KB
  int* bstart  = (int*)alloc((size_t)(NBUCK+1)*4);
  unsigned int* binbuf = (unsigned int*)alloc((size_t)E_TOTC*4);  // 3.4 MB
  float* exb1  = (float*)alloc((size_t)E_TOTC*HEADSC*4);   // 13.6 MB
  float* exb2  = (float*)alloc((size_t)E_TOTC*4);          // 3.4 MB

  k_gemm1<<<(N_NODESC+G1_ROWS-1)/G1_ROWS, 256, 0, stream>>>(x, W1, as1, ad1, h1b, al_s1, al_d1);
  k_binA<<<SBLK, 256, 0, stream>>>(ei, bh);
  k_binscan<<<1, 256, 0, stream>>>(bh, bstart);
  k_binB<<<SBLK, 256, 0, stream>>>(ei, bh, binbuf);
  k_binC<<<NBUCK, 256, 0, stream>>>(binbuf, bstart, rp, srcs);
  k_node1<<<(N_NODESC+3)/4, 256, 0, stream>>>(h1b, al_s1, al_d1, rp, srcs, b1, hout, exb1);
  k_gemm2<<<N_NODESC/16, 256, 0, stream>>>(hout, W2, as2, ad2, h2, al_s2, al_d2);
  k_node2<<<(N_NODESC+3)/4, 256, 0, stream>>>(h2, al_s2, al_d2, rp, srcs, b2, out, exb2);
}

// Round 9
// 184.467 us; speedup vs baseline: 1.5028x; 1.0074x over previous
//
#include <hip/hip_runtime.h>

#define N_NODESC 50000
#define E0C      800000
#define E_TOTC   850000
#define IN_CHC   128
#define HCC      128   // HEADS*HID
#define HEADSC   4
#define OUT_CHC  16
#define NEG_SLOPE 0.2f
#define G1_ROWS  32                          // rows per block in k_gemm1
#define NBUCK    196                         // ceil(50000/256) dst buckets
#define BNODES   256                         // nodes per bucket (dst>>8)
#define SBLK     128                         // binning blocks
#define CHUNK    6656                        // edges per binning block (128*6656 >= 850000)

__device__ __forceinline__ float lrelu(float v){ return v > 0.f ? v : NEG_SLOPE * v; }

// round-to-nearest-even fp32 -> bf16 (as uint16 in low bits)
__device__ __forceinline__ unsigned int f2bf(float f){
  unsigned int b = __float_as_uint(f);
  return (b + 0x7fffu + ((b >> 16) & 1u)) >> 16;
}
__device__ __forceinline__ float bf2f(unsigned int lo16){
  return __uint_as_float(lo16 << 16);
}
// xT column swizzle: XOR bits 2-4 with (k>>4)&7 -> conflict-free staging writes,
// contiguous 16B-aligned float4 reads (bits 0-1 untouched).
__device__ __forceinline__ int xswz(int r, int k){ return r ^ (((k >> 4) & 7) << 2); }

// h1 = x @ W1 (stored bf16-packed: uint = [c0+1 | c0]); al_s/al_d from fp32 accs.
__global__ void __launch_bounds__(256) k_gemm1(const float* __restrict__ x, const float* __restrict__ W1,
        const float* __restrict__ a_s, const float* __restrict__ a_d,
        unsigned int* __restrict__ h1b, float* __restrict__ al_s, float* __restrict__ al_d)
{
  __shared__ __align__(16) float Wl[IN_CHC*HCC];        // 64 KB
  __shared__ __align__(16) float xT[IN_CHC][G1_ROWS];   // 16 KB, [k][swz(row,k)]
  int tid = threadIdx.x;
  for (int i = tid*4; i < IN_CHC*HCC; i += 256*4)
    *(float4*)&Wl[i] = *(const float4*)&W1[i];
  int row0 = blockIdx.x * G1_ROWS;
  {
    int r  = tid >> 3;          // 0..31
    int kc = (tid & 7) * 16;    // 0..112
    int rr = row0 + r; if (rr > N_NODESC-1) rr = N_NODESC-1;   // clamp OOB reads
    const float* xp = &x[(size_t)rr*IN_CHC + kc];
    int sc = xswz(r, kc);       // (k>>4) constant over the 16-k chunk
    #pragma unroll
    for (int j = 0; j < 16; j += 4){
      float4 v = *(const float4*)&xp[j];
      xT[kc+j+0][sc] = v.x;
      xT[kc+j+1][sc] = v.y;
      xT[kc+j+2][sc] = v.z;
      xT[kc+j+3][sc] = v.w;
    }
  }
  __syncthreads();
  int wave = tid >> 6, lane = tid & 63;
  int c0 = lane * 2;
  int rbase = wave * 8;
  float acc[8][2];
  #pragma unroll
  for (int j = 0; j < 8; j++){ acc[j][0] = 0.f; acc[j][1] = 0.f; }
  #pragma unroll 4
  for (int k = 0; k < IN_CHC; k++){
    float2 w  = *(const float2*)&Wl[k*HCC + c0];
    int sa = xswz(rbase, k), sb = xswz(rbase+4, k);
    float4 xa = *(const float4*)&xT[k][sa];      // rows rbase..+3 (uniform)
    float4 xb = *(const float4*)&xT[k][sb];      // rows rbase+4..+7 (uniform)
    acc[0][0] = fmaf(xa.x, w.x, acc[0][0]); acc[0][1] = fmaf(xa.x, w.y, acc[0][1]);
    acc[1][0] = fmaf(xa.y, w.x, acc[1][0]); acc[1][1] = fmaf(xa.y, w.y, acc[1][1]);
    acc[2][0] = fmaf(xa.z, w.x, acc[2][0]); acc[2][1] = fmaf(xa.z, w.y, acc[2][1]);
    acc[3][0] = fmaf(xa.w, w.x, acc[3][0]); acc[3][1] = fmaf(xa.w, w.y, acc[3][1]);
    acc[4][0] = fmaf(xb.x, w.x, acc[4][0]); acc[4][1] = fmaf(xb.x, w.y, acc[4][1]);
    acc[5][0] = fmaf(xb.y, w.x, acc[5][0]); acc[5][1] = fmaf(xb.y, w.y, acc[5][1]);
    acc[6][0] = fmaf(xb.z, w.x, acc[6][0]); acc[6][1] = fmaf(xb.z, w.y, acc[6][1]);
    acc[7][0] = fmaf(xb.w, w.x, acc[7][0]); acc[7][1] = fmaf(xb.w, w.y, acc[7][1]);
  }
  float as0 = a_s[c0], as1 = a_s[c0+1];
  float ad0 = a_d[c0], ad1 = a_d[c0+1];
  #pragma unroll
  for (int j = 0; j < 8; j++){
    int row = row0 + rbase + j;
    if (row >= N_NODESC) break;
    h1b[(size_t)row*64 + lane] = f2bf(acc[j][0]) | (f2bf(acc[j][1]) << 16);
    float ps = acc[j][0]*as0 + acc[j][1]*as1;
    float pd = acc[j][0]*ad0 + acc[j][1]*ad1;
    #pragma unroll
    for (int m = 1; m < 16; m <<= 1){ ps += __shfl_xor(ps, m, 64); pd += __shfl_xor(pd, m, 64); }
    if ((lane & 15) == 0){
      al_s[row*HEADSC + (lane>>4)] = ps;
      al_d[row*HEADSC + (lane>>4)] = pd;
    }
  }
}

// --- binned CSR build: A) per-block bucket hist, scan) offsets, B) bin write, C) per-bucket scatter ---
__global__ void __launch_bounds__(256) k_binA(const int* __restrict__ ei, int* __restrict__ bh){
  __shared__ int h[NBUCK];
  int tid = threadIdx.x, b = blockIdx.x;
  for (int i = tid; i < NBUCK; i += 256) h[i] = 0;
  __syncthreads();
  int e0 = b*CHUNK, e1 = e0 + CHUNK; if (e1 > E_TOTC) e1 = E_TOTC;
  for (int e = e0 + tid; e < e1; e += 256){
    int d = (e < E0C) ? ei[E0C + e] : (e - E0C);
    atomicAdd(&h[d >> 8], 1);
  }
  __syncthreads();
  for (int i = tid; i < NBUCK; i += 256) bh[b*NBUCK + i] = h[i];
}

// single block: bh[b][k] -> per-(block,bucket) base in binbuf; bstart[k] = CSR/bin start per bucket
__global__ void __launch_bounds__(256) k_binscan(int* __restrict__ bh, int* __restrict__ bstart){
  __shared__ int buf[256];
  int tid = threadIdx.x;
  int tot = 0;
  if (tid < NBUCK)
    for (int b = 0; b < SBLK; b++) tot += bh[b*NBUCK + tid];
  buf[tid] = (tid < NBUCK) ? tot : 0;
  __syncthreads();
  #pragma unroll
  for (int off = 1; off < 256; off <<= 1){
    int t = (tid >= off) ? buf[tid - off] : 0;
    __syncthreads();
    buf[tid] += t; __syncthreads();
  }
  int excl = buf[tid] - ((tid < NBUCK) ? tot : 0);
  if (tid < NBUCK) bstart[tid] = excl;
  if (tid == 0) bstart[NBUCK] = E_TOTC;
  __syncthreads();
  if (tid < NBUCK){
    int run = excl;
    for (int b = 0; b < SBLK; b++){
      int t = bh[b*NBUCK + tid];
      bh[b*NBUCK + tid] = run;
      run += t;
    }
  }
}

__global__ void __launch_bounds__(256) k_binB(const int* __restrict__ ei, const int* __restrict__ bh,
                                              unsigned int* __restrict__ binbuf){
  __shared__ int h[NBUCK];
  int tid = threadIdx.x, b = blockIdx.x;
  for (int i = tid; i < NBUCK; i += 256) h[i] = bh[b*NBUCK + i];
  __syncthreads();
  int e0 = b*CHUNK, e1 = e0 + CHUNK; if (e1 > E_TOTC) e1 = E_TOTC;
  for (int e = e0 + tid; e < e1; e += 256){
    int s, d;
    if (e < E0C){ d = ei[E0C + e]; s = ei[e]; }
    else { s = e - E0C; d = s; }
    int pos = atomicAdd(&h[d >> 8], 1);
    binbuf[pos] = ((unsigned int)d << 16) | (unsigned int)s;
  }
}

// one block per bucket: local hist -> scan -> rp + final srcs scatter (L2-local writes)
__global__ void __launch_bounds__(256) k_binC(const unsigned int* __restrict__ binbuf,
                                              const int* __restrict__ bstart,
                                              int* __restrict__ rp, int* __restrict__ srcs){
  __shared__ int lcnt[BNODES];
  __shared__ int buf[BNODES];
  __shared__ int pfx[BNODES];
  int tid = threadIdx.x, k = blockIdx.x;
  int lo = k * BNODES;
  int b0 = bstart[k], b1 = bstart[k+1];
  lcnt[tid] = 0;
  __syncthreads();
  for (int i = b0 + tid; i < b1; i += 256){
    int d = binbuf[i] >> 16;
    atomicAdd(&lcnt[d - lo], 1);
  }
  __syncthreads();
  int v = lcnt[tid];
  buf[tid] = v;
  __syncthreads();
  #pragma unroll
  for (int off = 1; off < 256; off <<= 1){
    int t = (tid >= off) ? buf[tid - off] : 0;
    __syncthreads();
    buf[tid] += t; __syncthreads();
  }
  int excl = buf[tid] - v;
  pfx[tid] = excl;
  int node = lo + tid;
  if (node < N_NODESC) rp[node] = b0 + excl;
  if (k == 0 && tid == 0) rp[N_NODESC] = E_TOTC;
  lcnt[tid] = 0;
  __syncthreads();
  for (int i = b0 + tid; i < b1; i += 256){
    unsigned int u = binbuf[i];
    int d = u >> 16;
    int r = atomicAdd(&lcnt[d - lo], 1);
    srcs[b0 + pfx[d - lo] + r] = (int)(u & 0xffffu);
  }
}

// Layer-1. exp store + denom (pass A), bf16 gather + FMA aggregate (pass B).
__global__ void __launch_bounds__(256) k_node1(const unsigned int* __restrict__ h1b,
        const float* __restrict__ al_s, const float* __restrict__ al_d,
        const int* __restrict__ rp, const int* __restrict__ srcs,
        const float* __restrict__ b1, float* __restrict__ hout, float* __restrict__ exb)
{
  int wave = threadIdx.x >> 6, lane = threadIdx.x & 63;
  int n = blockIdx.x*4 + wave;
  if (n >= N_NODESC) return;
  int beg = rp[n], end = rp[n+1];
  float4 ad4 = *(const float4*)&al_d[n*4];
  float d0=0.f, d1=0.f, d2=0.f, d3=0.f;
  for (int p = beg + lane; p < end; p += 64){
    int s = srcs[p];
    float4 as = *(const float4*)&al_s[s*4];
    float4 ex;
    ex.x = __expf(lrelu(as.x + ad4.x));
    ex.y = __expf(lrelu(as.y + ad4.y));
    ex.z = __expf(lrelu(as.z + ad4.z));
    ex.w = __expf(lrelu(as.w + ad4.w));
    *(float4*)&exb[(size_t)p*4] = ex;
    d0 += ex.x; d1 += ex.y; d2 += ex.z; d3 += ex.w;
  }
  #pragma unroll
  for (int o = 1; o < 64; o <<= 1){
    d0 += __shfl_xor(d0, o, 64);
    d1 += __shfl_xor(d1, o, 64);
    d2 += __shfl_xor(d2, o, 64);
    d3 += __shfl_xor(d3, o, 64);
  }
  __threadfence_block();
  int h = lane >> 4;
  float dh  = (h==0) ? d0 : (h==1) ? d1 : (h==2) ? d2 : d3;
  float inv = 1.f / (dh + 1e-16f);
  float acc0 = 0.f, acc1 = 0.f;
  #pragma unroll 4
  for (int p = beg; p < end; p++){
    float a = exb[(size_t)p*4 + h];
    unsigned int u = h1b[(size_t)srcs[p]*64 + lane];
    acc0 = fmaf(a, bf2f(u & 0xffffu), acc0);
    acc1 = fmaf(a, bf2f(u >> 16), acc1);
  }
  int c0 = lane*2;
  float o0 = acc0*inv + b1[c0], o1 = acc1*inv + b1[c0+1];
  o0 = o0 > 0.f ? o0 : __expf(o0) - 1.f;   // ELU
  o1 = o1 > 0.f ? o1 : __expf(o1) - 1.f;
  *(float2*)&hout[(size_t)n*HCC + c0] = make_float2(o0, o1);
}

// h2 = hout @ W2 ; scalar attention logits (H=1,C=16). 4 rows per wave.
__global__ void __launch_bounds__(256) k_gemm2(const float* __restrict__ hin, const float* __restrict__ W2,
        const float* __restrict__ a_s, const float* __restrict__ a_d,
        float* __restrict__ h2, float* __restrict__ al_s, float* __restrict__ al_d)
{
  __shared__ __align__(16) float Wl[IN_CHC*OUT_CHC];   // 8 KB
  __shared__ __align__(16) float xr[4][4][IN_CHC];     // 8 KB
  int tid = threadIdx.x;
  for (int i = tid*4; i < IN_CHC*OUT_CHC; i += 256*4)
    *(float4*)&Wl[i] = *(const float4*)&W2[i];
  __syncthreads();
  int wave = tid >> 6, lane = tid & 63;
  int r = lane >> 4, c = lane & 15;
  int row0 = blockIdx.x*16 + wave*4;
  for (int rr = 0; rr < 4; rr++){
    float2 v = *(const float2*)&hin[(size_t)(row0+rr)*IN_CHC + lane*2];
    *(float2*)&xr[wave][rr][lane*2] = v;
  }
  float acc = 0.f;
  #pragma unroll 8
  for (int k = 0; k < IN_CHC; k++)
    acc = fmaf(xr[wave][r][k], Wl[k*OUT_CHC + c], acc);
  int row = row0 + r;
  h2[row*OUT_CHC + c] = acc;
  float ps = acc * a_s[c];
  float pd = acc * a_d[c];
  #pragma unroll
  for (int m = 1; m < 16; m <<= 1){ ps += __shfl_xor(ps, m, 64); pd += __shfl_xor(pd, m, 64); }
  if (c == 0){ al_s[row] = ps; al_d[row] = pd; }
}

// Layer-2: exp store + denom + aggregate + log_softmax (no max subtraction).
__global__ void __launch_bounds__(256) k_node2(const float* __restrict__ h2,
        const float* __restrict__ al_s, const float* __restrict__ al_d,
        const int* __restrict__ rp, const int* __restrict__ srcs,
        const float* __restrict__ b2, float* __restrict__ out, float* __restrict__ exb)
{
  int wave = threadIdx.x >> 6, lane = threadIdx.x & 63;
  int n = blockIdx.x*4 + wave;
  if (n >= N_NODESC) return;
  int beg = rp[n], end = rp[n+1];
  float ad = al_d[n];
  float den = 0.f;
  for (int p = beg + lane; p < end; p += 64){
    float ex = __expf(lrelu(al_s[srcs[p]] + ad));
    exb[p] = ex;
    den += ex;
  }
  #pragma unroll
  for (int o = 1; o < 64; o <<= 1) den += __shfl_xor(den, o, 64);
  __threadfence_block();
  float inv = 1.f / (den + 1e-16f);
  int c = lane & 15, j = lane >> 4;
  float acc = 0.f;
  #pragma unroll 4
  for (int p = beg + j; p < end; p += 4){
    int s = srcs[p];
    acc = fmaf(exb[p], h2[s*OUT_CHC + c], acc);
  }
  acc += __shfl_xor(acc, 16, 64);
  acc += __shfl_xor(acc, 32, 64);
  float v = acc*inv + b2[c];
  float mm = v;
  #pragma unroll
  for (int o = 1; o < 16; o <<= 1) mm = fmaxf(mm, __shfl_xor(mm, o, 64));
  float se = __expf(v - mm);
  #pragma unroll
  for (int o = 1; o < 16; o <<= 1) se += __shfl_xor(se, o, 64);
  if (j == 0) out[n*OUT_CHC + c] = v - mm - __logf(se);
}

extern "C" void kernel_launch(void* const* d_in, const int* in_sizes, int n_in,
                              void* d_out, int out_size, void* d_ws, size_t ws_size,
                              hipStream_t stream)
{
  const float* x   = (const float*)d_in[0];
  const int*   ei  = (const int*)d_in[1];
  // d_in[2] edge_attr: ignored (PyG GATConv with edge_dim=None)
  const float* W1  = (const float*)d_in[3];
  const float* as1 = (const float*)d_in[4];
  const float* ad1 = (const float*)d_in[5];
  const float* b1  = (const float*)d_in[6];
  const float* W2  = (const float*)d_in[7];
  const float* as2 = (const float*)d_in[8];
  const float* ad2 = (const float*)d_in[9];
  const float* b2  = (const float*)d_in[10];
  float* out = (float*)d_out;

  char* ws = (char*)d_ws;
  size_t off = 0;
  auto alloc = [&](size_t bytes)->void*{
    void* p = ws + off;
    off = (off + bytes + 255) & ~(size_t)255;
    return p;
  };
  unsigned int* h1b = (unsigned int*)alloc((size_t)N_NODESC*64*4);  // bf16-packed, 12.8 MB
  float* hout  = (float*)alloc((size_t)N_NODESC*HCC*4);
  float* al_s1 = (float*)alloc((size_t)N_NODESC*HEADSC*4);
  float* al_d1 = (float*)alloc((size_t)N_NODESC*HEADSC*4);
  float* h2    = (float*)alloc((size_t)N_NODESC*OUT_CHC*4);
  float* al_s2 = (float*)alloc((size_t)N_NODESC*4);
  float* al_d2 = (float*)alloc((size_t)N_NODESC*4);
  int* rp      = (int*)alloc((size_t)(N_NODESC+1)*4);
  int* srcs    = (int*)alloc((size_t)E_TOTC*4);
  int* bh      = (int*)alloc((size_t)SBLK*NBUCK*4);        // 100 KB
  int* bstart  = (int*)alloc((size_t)(NBUCK+1)*4);
  unsigned int* binbuf = (unsigned int*)alloc((size_t)E_TOTC*4);  // 3.4 MB
  float* exb1  = (float*)alloc((size_t)E_TOTC*HEADSC*4);   // 13.6 MB
  float* exb2  = (float*)alloc((size_t)E_TOTC*4);          // 3.4 MB

  k_gemm1<<<(N_NODESC+G1_ROWS-1)/G1_ROWS, 256, 0, stream>>>(x, W1, as1, ad1, h1b, al_s1, al_d1);
  k_binA<<<SBLK, 256, 0, stream>>>(ei, bh);
  k_binscan<<<1, 256, 0, stream>>>(bh, bstart);
  k_binB<<<SBLK, 256, 0, stream>>>(ei, bh, binbuf);
  k_binC<<<NBUCK, 256, 0, stream>>>(binbuf, bstart, rp, srcs);
  k_node1<<<(N_NODESC+3)/4, 256, 0, stream>>>(h1b, al_s1, al_d1, rp, srcs, b1, hout, exb1);
  k_gemm2<<<N_NODESC/16, 256, 0, stream>>>(hout, W2, as2, ad2, h2, al_s2, al_d2);
  k_node2<<<(N_NODESC+3)/4, 256, 0, stream>>>(h2, al_s2, al_d2, rp, srcs, b2, out, exb2);
}

// Round 10
// 179.557 us; speedup vs baseline: 1.5439x; 1.0273x over previous
//
#include <hip/hip_runtime.h>

#define N_NODESC 50000
#define E0C      800000
#define E_TOTC   850000
#define IN_CHC   128
#define HCC      128   // HEADS*HID
#define HEADSC   4
#define OUT_CHC  16
#define NEG_SLOPE 0.2f
#define G1_ROWS  32                          // rows per block in k_gemm1
#define NBUCK    196                         // ceil(50000/256) dst buckets
#define BNODES   256                         // nodes per bucket (dst>>8)
#define SBLK     128                         // binning blocks
#define CHUNK    6656                        // edges per binning block (128*6656 >= 850000)

__device__ __forceinline__ float lrelu(float v){ return v > 0.f ? v : NEG_SLOPE * v; }

// round-to-nearest-even fp32 -> bf16 (as uint16 in low bits)
__device__ __forceinline__ unsigned int f2bf(float f){
  unsigned int b = __float_as_uint(f);
  return (b + 0x7fffu + ((b >> 16) & 1u)) >> 16;
}
__device__ __forceinline__ float bf2f(unsigned int lo16){
  return __uint_as_float(lo16 << 16);
}
// xT column swizzle: XOR bits 2-4 with (k>>4)&7 -> conflict-free staging writes,
// contiguous 16B-aligned float4 reads (bits 0-1 untouched).
__device__ __forceinline__ int xswz(int r, int k){ return r ^ (((k >> 4) & 7) << 2); }

// h1 = x @ W1 (bf16-packed out). 512 threads / 8 waves, 4 rows per wave.
// 80 KB LDS -> 2 blocks/CU = 16 waves/CU = 4 waves/SIMD (2x round-9 occupancy).
__global__ void __launch_bounds__(512) k_gemm1(const float* __restrict__ x, const float* __restrict__ W1,
        const float* __restrict__ a_s, const float* __restrict__ a_d,
        unsigned int* __restrict__ h1b, float* __restrict__ al_s, float* __restrict__ al_d)
{
  __shared__ __align__(16) float Wl[IN_CHC*HCC];        // 64 KB
  __shared__ __align__(16) float xT[IN_CHC][G1_ROWS];   // 16 KB, [k][swz(row,k)]
  int tid = threadIdx.x;
  for (int i = tid*4; i < IN_CHC*HCC; i += 512*4)
    *(float4*)&Wl[i] = *(const float4*)&W1[i];
  int row0 = blockIdx.x * G1_ROWS;
  {
    int r  = tid >> 4;          // 0..31
    int kc = (tid & 15) * 8;    // 0..120
    int rr = row0 + r; if (rr > N_NODESC-1) rr = N_NODESC-1;   // clamp OOB reads
    const float* xp = &x[(size_t)rr*IN_CHC + kc];
    int sc = xswz(r, kc);       // (k>>4) constant over the 8-k chunk
    #pragma unroll
    for (int j = 0; j < 8; j += 4){
      float4 v = *(const float4*)&xp[j];
      xT[kc+j+0][sc] = v.x;
      xT[kc+j+1][sc] = v.y;
      xT[kc+j+2][sc] = v.z;
      xT[kc+j+3][sc] = v.w;
    }
  }
  __syncthreads();
  int wave = tid >> 6, lane = tid & 63;
  int c0 = lane * 2;
  int rbase = wave * 4;
  float acc[4][2];
  #pragma unroll
  for (int j = 0; j < 4; j++){ acc[j][0] = 0.f; acc[j][1] = 0.f; }
  #pragma unroll 4
  for (int k = 0; k < IN_CHC; k++){
    float2 w  = *(const float2*)&Wl[k*HCC + c0];
    float4 xa = *(const float4*)&xT[k][xswz(rbase, k)];   // rows rbase..+3 (uniform)
    acc[0][0] = fmaf(xa.x, w.x, acc[0][0]); acc[0][1] = fmaf(xa.x, w.y, acc[0][1]);
    acc[1][0] = fmaf(xa.y, w.x, acc[1][0]); acc[1][1] = fmaf(xa.y, w.y, acc[1][1]);
    acc[2][0] = fmaf(xa.z, w.x, acc[2][0]); acc[2][1] = fmaf(xa.z, w.y, acc[2][1]);
    acc[3][0] = fmaf(xa.w, w.x, acc[3][0]); acc[3][1] = fmaf(xa.w, w.y, acc[3][1]);
  }
  float as0 = a_s[c0], as1 = a_s[c0+1];
  float ad0 = a_d[c0], ad1 = a_d[c0+1];
  #pragma unroll
  for (int j = 0; j < 4; j++){
    int row = row0 + rbase + j;
    if (row >= N_NODESC) break;
    h1b[(size_t)row*64 + lane] = f2bf(acc[j][0]) | (f2bf(acc[j][1]) << 16);
    float ps = acc[j][0]*as0 + acc[j][1]*as1;
    float pd = acc[j][0]*ad0 + acc[j][1]*ad1;
    #pragma unroll
    for (int m = 1; m < 16; m <<= 1){ ps += __shfl_xor(ps, m, 64); pd += __shfl_xor(pd, m, 64); }
    if ((lane & 15) == 0){
      al_s[row*HEADSC + (lane>>4)] = ps;
      al_d[row*HEADSC + (lane>>4)] = pd;
    }
  }
}

// --- binned CSR build: A) per-block bucket hist, scan) offsets, B) bin write, C) per-bucket scatter ---
__global__ void __launch_bounds__(256) k_binA(const int* __restrict__ ei, int* __restrict__ bh){
  __shared__ int h[NBUCK];
  int tid = threadIdx.x, b = blockIdx.x;
  for (int i = tid; i < NBUCK; i += 256) h[i] = 0;
  __syncthreads();
  int e0 = b*CHUNK, e1 = e0 + CHUNK; if (e1 > E_TOTC) e1 = E_TOTC;
  for (int e = e0 + tid; e < e1; e += 256){
    int d = (e < E0C) ? ei[E0C + e] : (e - E0C);
    atomicAdd(&h[d >> 8], 1);
  }
  __syncthreads();
  for (int i = tid; i < NBUCK; i += 256) bh[b*NBUCK + i] = h[i];
}

// single block: bh[b][k] -> per-(block,bucket) base in binbuf; bstart[k] = CSR/bin start per bucket
__global__ void __launch_bounds__(256) k_binscan(int* __restrict__ bh, int* __restrict__ bstart){
  __shared__ int buf[256];
  int tid = threadIdx.x;
  int tot = 0;
  if (tid < NBUCK)
    for (int b = 0; b < SBLK; b++) tot += bh[b*NBUCK + tid];
  buf[tid] = (tid < NBUCK) ? tot : 0;
  __syncthreads();
  #pragma unroll
  for (int off = 1; off < 256; off <<= 1){
    int t = (tid >= off) ? buf[tid - off] : 0;
    __syncthreads();
    buf[tid] += t; __syncthreads();
  }
  int excl = buf[tid] - ((tid < NBUCK) ? tot : 0);
  if (tid < NBUCK) bstart[tid] = excl;
  if (tid == 0) bstart[NBUCK] = E_TOTC;
  __syncthreads();
  if (tid < NBUCK){
    int run = excl;
    for (int b = 0; b < SBLK; b++){
      int t = bh[b*NBUCK + tid];
      bh[b*NBUCK + tid] = run;
      run += t;
    }
  }
}

__global__ void __launch_bounds__(256) k_binB(const int* __restrict__ ei, const int* __restrict__ bh,
                                              unsigned int* __restrict__ binbuf){
  __shared__ int h[NBUCK];
  int tid = threadIdx.x, b = blockIdx.x;
  for (int i = tid; i < NBUCK; i += 256) h[i] = bh[b*NBUCK + i];
  __syncthreads();
  int e0 = b*CHUNK, e1 = e0 + CHUNK; if (e1 > E_TOTC) e1 = E_TOTC;
  for (int e = e0 + tid; e < e1; e += 256){
    int s, d;
    if (e < E0C){ d = ei[E0C + e]; s = ei[e]; }
    else { s = e - E0C; d = s; }
    int pos = atomicAdd(&h[d >> 8], 1);
    binbuf[pos] = ((unsigned int)d << 16) | (unsigned int)s;
  }
}

// one block per bucket: local hist -> scan -> rp + final srcs scatter (L2-local writes)
__global__ void __launch_bounds__(256) k_binC(const unsigned int* __restrict__ binbuf,
                                              const int* __restrict__ bstart,
                                              int* __restrict__ rp, int* __restrict__ srcs){
  __shared__ int lcnt[BNODES];
  __shared__ int buf[BNODES];
  __shared__ int pfx[BNODES];
  int tid = threadIdx.x, k = blockIdx.x;
  int lo = k * BNODES;
  int b0 = bstart[k], b1 = bstart[k+1];
  lcnt[tid] = 0;
  __syncthreads();
  for (int i = b0 + tid; i < b1; i += 256){
    int d = binbuf[i] >> 16;
    atomicAdd(&lcnt[d - lo], 1);
  }
  __syncthreads();
  int v = lcnt[tid];
  buf[tid] = v;
  __syncthreads();
  #pragma unroll
  for (int off = 1; off < 256; off <<= 1){
    int t = (tid >= off) ? buf[tid - off] : 0;
    __syncthreads();
    buf[tid] += t; __syncthreads();
  }
  int excl = buf[tid] - v;
  pfx[tid] = excl;
  int node = lo + tid;
  if (node < N_NODESC) rp[node] = b0 + excl;
  if (k == 0 && tid == 0) rp[N_NODESC] = E_TOTC;
  lcnt[tid] = 0;
  __syncthreads();
  for (int i = b0 + tid; i < b1; i += 256){
    unsigned int u = binbuf[i];
    int d = u >> 16;
    int r = atomicAdd(&lcnt[d - lo], 1);
    srcs[b0 + pfx[d - lo] + r] = (int)(u & 0xffffu);
  }
}

// Layer-1: denom pass (strided), then aggregate pass with recomputed __expf (no exb buffer).
__global__ void __launch_bounds__(256) k_node1(const unsigned int* __restrict__ h1b,
        const float* __restrict__ al_s, const float* __restrict__ al_d,
        const int* __restrict__ rp, const int* __restrict__ srcs,
        const float* __restrict__ b1, float* __restrict__ hout)
{
  int wave = threadIdx.x >> 6, lane = threadIdx.x & 63;
  int n = blockIdx.x*4 + wave;
  if (n >= N_NODESC) return;
  int beg = rp[n], end = rp[n+1];
  float4 ad4 = *(const float4*)&al_d[n*4];
  float d0=0.f, d1=0.f, d2=0.f, d3=0.f;
  for (int p = beg + lane; p < end; p += 64){
    int s = srcs[p];
    float4 as = *(const float4*)&al_s[s*4];
    d0 += __expf(lrelu(as.x + ad4.x));
    d1 += __expf(lrelu(as.y + ad4.y));
    d2 += __expf(lrelu(as.z + ad4.z));
    d3 += __expf(lrelu(as.w + ad4.w));
  }
  #pragma unroll
  for (int o = 1; o < 64; o <<= 1){
    d0 += __shfl_xor(d0, o, 64);
    d1 += __shfl_xor(d1, o, 64);
    d2 += __shfl_xor(d2, o, 64);
    d3 += __shfl_xor(d3, o, 64);
  }
  int h = lane >> 4;
  float dh  = (h==0) ? d0 : (h==1) ? d1 : (h==2) ? d2 : d3;
  float adh = (h==0) ? ad4.x : (h==1) ? ad4.y : (h==2) ? ad4.z : ad4.w;
  float inv = 1.f / (dh + 1e-16f);
  float acc0 = 0.f, acc1 = 0.f;
  #pragma unroll 4
  for (int p = beg; p < end; p++){
    int s = srcs[p];
    float a = __expf(lrelu(al_s[s*4 + h] + adh));
    unsigned int u = h1b[(size_t)s*64 + lane];
    acc0 = fmaf(a, bf2f(u & 0xffffu), acc0);
    acc1 = fmaf(a, bf2f(u >> 16), acc1);
  }
  int c0 = lane*2;
  float o0 = acc0*inv + b1[c0], o1 = acc1*inv + b1[c0+1];
  o0 = o0 > 0.f ? o0 : __expf(o0) - 1.f;   // ELU
  o1 = o1 > 0.f ? o1 : __expf(o1) - 1.f;
  *(float2*)&hout[(size_t)n*HCC + c0] = make_float2(o0, o1);
}

// h2 = hout @ W2 ; scalar attention logits (H=1,C=16). 4 rows per wave.
__global__ void __launch_bounds__(256) k_gemm2(const float* __restrict__ hin, const float* __restrict__ W2,
        const float* __restrict__ a_s, const float* __restrict__ a_d,
        float* __restrict__ h2, float* __restrict__ al_s, float* __restrict__ al_d)
{
  __shared__ __align__(16) float Wl[IN_CHC*OUT_CHC];   // 8 KB
  __shared__ __align__(16) float xr[4][4][IN_CHC];     // 8 KB
  int tid = threadIdx.x;
  for (int i = tid*4; i < IN_CHC*OUT_CHC; i += 256*4)
    *(float4*)&Wl[i] = *(const float4*)&W2[i];
  __syncthreads();
  int wave = tid >> 6, lane = tid & 63;
  int r = lane >> 4, c = lane & 15;
  int row0 = blockIdx.x*16 + wave*4;
  for (int rr = 0; rr < 4; rr++){
    float2 v = *(const float2*)&hin[(size_t)(row0+rr)*IN_CHC + lane*2];
    *(float2*)&xr[wave][rr][lane*2] = v;
  }
  float acc = 0.f;
  #pragma unroll 8
  for (int k = 0; k < IN_CHC; k++)
    acc = fmaf(xr[wave][r][k], Wl[k*OUT_CHC + c], acc);
  int row = row0 + r;
  h2[row*OUT_CHC + c] = acc;
  float ps = acc * a_s[c];
  float pd = acc * a_d[c];
  #pragma unroll
  for (int m = 1; m < 16; m <<= 1){ ps += __shfl_xor(ps, m, 64); pd += __shfl_xor(pd, m, 64); }
  if (c == 0){ al_s[row] = ps; al_d[row] = pd; }
}

// Layer-2: denom + aggregate with recomputed __expf + log_softmax (no exb buffer).
__global__ void __launch_bounds__(256) k_node2(const float* __restrict__ h2,
        const float* __restrict__ al_s, const float* __restrict__ al_d,
        const int* __restrict__ rp, const int* __restrict__ srcs,
        const float* __restrict__ b2, float* __restrict__ out)
{
  int wave = threadIdx.x >> 6, lane = threadIdx.x & 63;
  int n = blockIdx.x*4 + wave;
  if (n >= N_NODESC) return;
  int beg = rp[n], end = rp[n+1];
  float ad = al_d[n];
  float den = 0.f;
  for (int p = beg + lane; p < end; p += 64)
    den += __expf(lrelu(al_s[srcs[p]] + ad));
  #pragma unroll
  for (int o = 1; o < 64; o <<= 1) den += __shfl_xor(den, o, 64);
  float inv = 1.f / (den + 1e-16f);
  int c = lane & 15, j = lane >> 4;
  float acc = 0.f;
  #pragma unroll 4
  for (int p = beg + j; p < end; p += 4){
    int s = srcs[p];
    float a = __expf(lrelu(al_s[s] + ad));
    acc = fmaf(a, h2[s*OUT_CHC + c], acc);
  }
  acc += __shfl_xor(acc, 16, 64);
  acc += __shfl_xor(acc, 32, 64);
  float v = acc*inv + b2[c];
  float mm = v;
  #pragma unroll
  for (int o = 1; o < 16; o <<= 1) mm = fmaxf(mm, __shfl_xor(mm, o, 64));
  float se = __expf(v - mm);
  #pragma unroll
  for (int o = 1; o < 16; o <<= 1) se += __shfl_xor(se, o, 64);
  if (j == 0) out[n*OUT_CHC + c] = v - mm - __logf(se);
}

extern "C" void kernel_launch(void* const* d_in, const int* in_sizes, int n_in,
                              void* d_out, int out_size, void* d_ws, size_t ws_size,
                              hipStream_t stream)
{
  const float* x   = (const float*)d_in[0];
  const int*   ei  = (const int*)d_in[1];
  // d_in[2] edge_attr: ignored (PyG GATConv with edge_dim=None)
  const float* W1  = (const float*)d_in[3];
  const float* as1 = (const float*)d_in[4];
  const float* ad1 = (const float*)d_in[5];
  const float* b1  = (const float*)d_in[6];
  const float* W2  = (const float*)d_in[7];
  const float* as2 = (const float*)d_in[8];
  const float* ad2 = (const float*)d_in[9];
  const float* b2  = (const float*)d_in[10];
  float* out = (float*)d_out;

  char* ws = (char*)d_ws;
  size_t off = 0;
  auto alloc = [&](size_t bytes)->void*{
    void* p = ws + off;
    off = (off + bytes + 255) & ~(size_t)255;
    return p;
  };
  unsigned int* h1b = (unsigned int*)alloc((size_t)N_NODESC*64*4);  // bf16-packed, 12.8 MB
  float* hout  = (float*)alloc((size_t)N_NODESC*HCC*4);
  float* al_s1 = (float*)alloc((size_t)N_NODESC*HEADSC*4);
  float* al_d1 = (float*)alloc((size_t)N_NODESC*HEADSC*4);
  float* h2    = (float*)alloc((size_t)N_NODESC*OUT_CHC*4);
  float* al_s2 = (float*)alloc((size_t)N_NODESC*4);
  float* al_d2 = (float*)alloc((size_t)N_NODESC*4);
  int* rp      = (int*)alloc((size_t)(N_NODESC+1)*4);
  int* srcs    = (int*)alloc((size_t)E_TOTC*4);
  int* bh      = (int*)alloc((size_t)SBLK*NBUCK*4);        // 100 KB
  int* bstart  = (int*)alloc((size_t)(NBUCK+1)*4);
  unsigned int* binbuf = (unsigned int*)alloc((size_t)E_TOTC*4);  // 3.4 MB

  k_gemm1<<<(N_NODESC+G1_ROWS-1)/G1_ROWS, 512, 0, stream>>>(x, W1, as1, ad1, h1b, al_s1, al_d1);
  k_binA<<<SBLK, 256, 0, stream>>>(ei, bh);
  k_binscan<<<1, 256, 0, stream>>>(bh, bstart);
  k_binB<<<SBLK, 256, 0, stream>>>(ei, bh, binbuf);
  k_binC<<<NBUCK, 256, 0, stream>>>(binbuf, bstart, rp, srcs);
  k_node1<<<(N_NODESC+3)/4, 256, 0, stream>>>(h1b, al_s1, al_d1, rp, srcs, b1, hout);
  k_gemm2<<<N_NODESC/16, 256, 0, stream>>>(hout, W2, as2, ad2, h2, al_s2, al_d2);
  k_node2<<<(N_NODESC+3)/4, 256, 0, stream>>>(h2, al_s2, al_d2, rp, srcs, b2, out);
}